// Round 1
// baseline (1407.103 us; speedup 1.0000x reference)
//
#include <hip/hip_runtime.h>
#include <hip/hip_bf16.h>
#include <stdint.h>

// Problem constants
#define BB   8192   // batch
#define DD   8      // features
#define PP   10     // poly basis width
#define RR   512    // TT rank
#define OUTD 64     // output dim
#define KK   5120   // expanded K = PP*RR (j-major: kk = j*512 + i)

typedef __bf16 bf16x8 __attribute__((ext_vector_type(8)));
typedef float  f32x4  __attribute__((ext_vector_type(4)));

__device__ __forceinline__ void gload_lds16(const __hip_bfloat16* g, __hip_bfloat16* l) {
    __builtin_amdgcn_global_load_lds(
        (const __attribute__((address_space(1))) void*)g,
        (__attribute__((address_space(3))) void*)l, 16, 0, 0);
}

// ---------------------------------------------------------------------------
// Prep: tanh + transpose G_mid[c][i][j][k] -> tB[c][k][j*512 + i]  (bf16)
// grid (16,16,60) = (i-tile, k-tile, c*10+j), block (32,8)
// ---------------------------------------------------------------------------
__global__ __launch_bounds__(256) void tanh_transpose_mid(
        const float* __restrict__ G, __hip_bfloat16* __restrict__ tB) {
    __shared__ float t[32][33];
    const int cj = blockIdx.z;
    const int c  = cj / 10, j = cj % 10;
    const int i0 = blockIdx.x * 32, k0 = blockIdx.y * 32;
    const float* src = G + (size_t)c * (RR * PP * RR) + (size_t)j * RR;
    #pragma unroll
    for (int q = 0; q < 4; ++q) {
        int i = i0 + threadIdx.y + q * 8;
        int k = k0 + threadIdx.x;
        t[threadIdx.y + q * 8][threadIdx.x] = src[(size_t)i * (PP * RR) + k];
    }
    __syncthreads();
    __hip_bfloat16* dst = tB + (size_t)c * (RR * KK) + (size_t)j * RR;
    #pragma unroll
    for (int q = 0; q < 4; ++q) {
        int k = k0 + threadIdx.y + q * 8;
        int i = i0 + threadIdx.x;
        dst[(size_t)k * KK + i] = __float2bfloat16(tanhf(t[threadIdx.x][threadIdx.y + q * 8]));
    }
}

// ---------------------------------------------------------------------------
// Prep: tanh + transpose G_last[i][j][l] -> tB[l][j*512 + i]  (bf16)
// grid (16,2,10) = (i-tile, l-tile, j), block (32,8)
// ---------------------------------------------------------------------------
__global__ __launch_bounds__(256) void tanh_transpose_last(
        const float* __restrict__ G, __hip_bfloat16* __restrict__ tB) {
    __shared__ float t[32][33];
    const int j  = blockIdx.z;
    const int i0 = blockIdx.x * 32, l0 = blockIdx.y * 32;
    #pragma unroll
    for (int q = 0; q < 4; ++q) {
        int i = i0 + threadIdx.y + q * 8;
        int l = l0 + threadIdx.x;
        t[threadIdx.y + q * 8][threadIdx.x] = G[(size_t)i * (PP * OUTD) + (size_t)j * OUTD + l];
    }
    __syncthreads();
    #pragma unroll
    for (int q = 0; q < 4; ++q) {
        int l = l0 + threadIdx.y + q * 8;
        int i = i0 + threadIdx.x;
        tB[(size_t)l * KK + (size_t)j * RR + i] =
            __float2bfloat16(tanhf(t[threadIdx.x][threadIdx.y + q * 8]));
    }
}

// ---------------------------------------------------------------------------
// First core: res0[b,r] = sum_j tanh(G0[j,r]) * z[b,0]^j   (fp32)
// grid 8192, block 512
// ---------------------------------------------------------------------------
__global__ __launch_bounds__(512) void tt_first(
        const float* __restrict__ z, const float* __restrict__ G0,
        float* __restrict__ res0) {
    __shared__ float sg[PP * RR];
    const int b = blockIdx.x;
    for (int x = threadIdx.x; x < PP * RR; x += 512) sg[x] = tanhf(G0[x]);
    __syncthreads();
    const float z0 = z[(size_t)b * DD + 0];
    const int r = threadIdx.x;
    float p = 1.0f, acc = 0.0f;
    #pragma unroll
    for (int j = 0; j < PP; ++j) { acc += sg[j * RR + r] * p; p *= z0; }
    res0[(size_t)b * RR + r] = acc;
}

// ---------------------------------------------------------------------------
// Fused-expansion GEMM:  out[b,n] = sum_kk (res[b,i]*z_b^j) * tB[n][kk]
//   kk = j*512 + i (j-major), BK=64 so j is constant per K-tile.
// BM=128 fixed; BN = 128 (mid cores) or 64 (last core).
// block 256 threads = 4 waves arranged 2x2 over (BM, BN).
// ---------------------------------------------------------------------------
template <int BN>
__global__ __launch_bounds__(256) void tt_gemm(
        const float* __restrict__ resin,
        const __hip_bfloat16* __restrict__ tB,
        float* __restrict__ resout,
        const float* __restrict__ z, int d, int nstride) {
    constexpr int BM = 128, BK = 64, LDA = 72;   // LDA padded: 2-way-free banks
    constexpr int SN  = BN / 32;                 // n-subtiles per wave
    constexpr int NCH = BN / 8;                  // 1KB global_load_lds chunks
    constexpr int CPW = NCH / 4;                 // chunks per wave

    __shared__ __hip_bfloat16 sA[BM * LDA];
    __shared__ __hip_bfloat16 sB[BN * BK];

    const int tid  = threadIdx.x;
    const int lane = tid & 63;
    const int wave = tid >> 6;
    const int m0 = blockIdx.y * BM;
    const int n0 = blockIdx.x * BN;

    // A-staging role: 2 threads per row, 32 contiguous elems each
    const int arow  = tid >> 1;
    const int acol0 = (tid & 1) * 32;
    const float zb  = z[(size_t)(m0 + arow) * DD + d];
    float p = 1.0f;  // z_b^j, advanced when K-tile crosses a j boundary

    // wave tile
    const int wm = (wave >> 1) * 64;
    const int wn = (wave & 1) * (BN / 2);

    f32x4 acc[4][SN];
    #pragma unroll
    for (int a = 0; a < 4; ++a)
        #pragma unroll
        for (int b = 0; b < SN; ++b) acc[a][b] = f32x4{0.f, 0.f, 0.f, 0.f};

    #pragma unroll 1
    for (int kk0 = 0; kk0 < KK; kk0 += BK) {
        if (kk0 && ((kk0 & 511) == 0)) p *= zb;

        // ---- B tile: async global->LDS, [n][k] bf16, rows of 128B ----
        #pragma unroll
        for (int q = 0; q < CPW; ++q) {
            const int ch = wave * CPW + q;
            const int r  = ch * 8 + (lane >> 3);
            const int cc = (lane & 7) * 8;
            gload_lds16(tB + (size_t)(n0 + r) * KK + kk0 + cc,
                        sB + ch * 512 + lane * 8);
        }

        // ---- A tile: res chunk * phi scalar -> bf16 LDS ----
        {
            const f32x4* src = (const f32x4*)(resin + (size_t)(m0 + arow) * RR + (kk0 & 511) + acol0);
            __hip_bfloat16* dstp = sA + arow * LDA + acol0;
            #pragma unroll
            for (int u = 0; u < 8; ++u) {
                f32x4 f = src[u];
                dstp[u * 4 + 0] = __float2bfloat16(f.x * p);
                dstp[u * 4 + 1] = __float2bfloat16(f.y * p);
                dstp[u * 4 + 2] = __float2bfloat16(f.z * p);
                dstp[u * 4 + 3] = __float2bfloat16(f.w * p);
            }
        }
        __syncthreads();

        // ---- MFMA: 2 K32 steps ----
        #pragma unroll
        for (int ks = 0; ks < 2; ++ks) {
            const int kb = ks * 32 + (lane >> 4) * 8;
            bf16x8 av[4], bv[SN];
            #pragma unroll
            for (int s = 0; s < 4; ++s)
                av[s] = *(const bf16x8*)(sA + (wm + s * 16 + (lane & 15)) * LDA + kb);
            #pragma unroll
            for (int s = 0; s < SN; ++s)
                bv[s] = *(const bf16x8*)(sB + (wn + s * 16 + (lane & 15)) * BK + kb);
            #pragma unroll
            for (int sm = 0; sm < 4; ++sm)
                #pragma unroll
                for (int sn = 0; sn < SN; ++sn)
                    acc[sm][sn] = __builtin_amdgcn_mfma_f32_16x16x32_bf16(
                        av[sm], bv[sn], acc[sm][sn], 0, 0, 0);
        }
        __syncthreads();
    }

    // ---- epilogue: C/D layout col=lane&15, row=(lane>>4)*4+reg ----
    const int col = lane & 15;
    const int rq  = (lane >> 4) * 4;
    #pragma unroll
    for (int sm = 0; sm < 4; ++sm)
        #pragma unroll
        for (int sn = 0; sn < SN; ++sn)
            #pragma unroll
            for (int r = 0; r < 4; ++r) {
                const int grow = m0 + wm + sm * 16 + rq + r;
                const int gcol = n0 + wn + sn * 16 + col;
                resout[(size_t)grow * nstride + gcol] = acc[sm][sn][r];
            }
}

// ---------------------------------------------------------------------------
extern "C" void kernel_launch(void* const* d_in, const int* in_sizes, int n_in,
                              void* d_out, int out_size, void* d_ws, size_t ws_size,
                              hipStream_t stream) {
    const float* z     = (const float*)d_in[0];
    const float* G0    = (const float*)d_in[1];
    const float* Gmid  = (const float*)d_in[2];
    const float* Glast = (const float*)d_in[3];
    float* out = (float*)d_out;

    char* ws = (char*)d_ws;
    float* resA = (float*)ws;                                  // 16 MB
    float* resB = (float*)(ws + ((size_t)16 << 20));           // 16 MB
    __hip_bfloat16* tBmid  = (__hip_bfloat16*)(ws + ((size_t)32 << 20)); // 31.5 MB
    __hip_bfloat16* tBlast = (__hip_bfloat16*)(ws + ((size_t)64 << 20)); // 0.64 MB

    tanh_transpose_mid <<<dim3(16, 16, 60), dim3(32, 8), 0, stream>>>(Gmid,  tBmid);
    tanh_transpose_last<<<dim3(16, 2, 10),  dim3(32, 8), 0, stream>>>(Glast, tBlast);
    tt_first<<<BB, 512, 0, stream>>>(z, G0, resA);

    float* rin = resA;
    float* rout = resB;
    for (int c = 0; c < 6; ++c) {
        tt_gemm<128><<<dim3(RR / 128, BB / 128), 256, 0, stream>>>(
            rin, tBmid + (size_t)c * RR * KK, rout, z, c + 1, RR);
        float* t = rin; rin = rout; rout = t;
    }
    tt_gemm<64><<<dim3(1, BB / 128), 256, 0, stream>>>(
        rin, tBlast, out, z, 7, OUTD);
}

// Round 2
// 512.543 us; speedup vs baseline: 2.7453x; 2.7453x over previous
//
#include <hip/hip_runtime.h>
#include <hip/hip_bf16.h>
#include <stdint.h>

// Problem constants
#define BB   8192   // batch
#define DD   8      // features
#define PP   10     // poly basis width
#define RR   512    // TT rank
#define OUTD 64     // output dim
#define KK   5120   // expanded K = PP*RR (j-major: kk = j*512 + i)

typedef __bf16 bf16x8 __attribute__((ext_vector_type(8)));
typedef float  f32x4  __attribute__((ext_vector_type(4)));

__device__ __forceinline__ void gload_lds16(const __hip_bfloat16* g, __hip_bfloat16* l) {
    __builtin_amdgcn_global_load_lds(
        (const __attribute__((address_space(1))) void*)g,
        (__attribute__((address_space(3))) void*)l, 16, 0, 0);
}

// ---------------------------------------------------------------------------
// Prep: tanh + transpose G_mid[c][i][j][k] -> tB[c][k][j*512 + i]  (bf16)
// ---------------------------------------------------------------------------
__global__ __launch_bounds__(256) void tanh_transpose_mid(
        const float* __restrict__ G, __hip_bfloat16* __restrict__ tB) {
    __shared__ float t[32][33];
    const int cj = blockIdx.z;
    const int c  = cj / 10, j = cj % 10;
    const int i0 = blockIdx.x * 32, k0 = blockIdx.y * 32;
    const float* src = G + (size_t)c * (RR * PP * RR) + (size_t)j * RR;
    #pragma unroll
    for (int q = 0; q < 4; ++q) {
        int i = i0 + threadIdx.y + q * 8;
        int k = k0 + threadIdx.x;
        t[threadIdx.y + q * 8][threadIdx.x] = src[(size_t)i * (PP * RR) + k];
    }
    __syncthreads();
    __hip_bfloat16* dst = tB + (size_t)c * (RR * KK) + (size_t)j * RR;
    #pragma unroll
    for (int q = 0; q < 4; ++q) {
        int k = k0 + threadIdx.y + q * 8;
        int i = i0 + threadIdx.x;
        dst[(size_t)k * KK + i] = __float2bfloat16(tanhf(t[threadIdx.x][threadIdx.y + q * 8]));
    }
}

// ---------------------------------------------------------------------------
// Prep: tanh + transpose G_last[i][j][l] -> tB[l][j*512 + i]  (bf16)
// ---------------------------------------------------------------------------
__global__ __launch_bounds__(256) void tanh_transpose_last(
        const float* __restrict__ G, __hip_bfloat16* __restrict__ tB) {
    __shared__ float t[32][33];
    const int j  = blockIdx.z;
    const int i0 = blockIdx.x * 32, l0 = blockIdx.y * 32;
    #pragma unroll
    for (int q = 0; q < 4; ++q) {
        int i = i0 + threadIdx.y + q * 8;
        int l = l0 + threadIdx.x;
        t[threadIdx.y + q * 8][threadIdx.x] = G[(size_t)i * (PP * OUTD) + (size_t)j * OUTD + l];
    }
    __syncthreads();
    #pragma unroll
    for (int q = 0; q < 4; ++q) {
        int l = l0 + threadIdx.y + q * 8;
        int i = i0 + threadIdx.x;
        tB[(size_t)l * KK + (size_t)j * RR + i] =
            __float2bfloat16(tanhf(t[threadIdx.x][threadIdx.y + q * 8]));
    }
}

// ---------------------------------------------------------------------------
// First core: res0[b,r] = sum_j tanh(G0[j,r]) * z[b,0]^j  -> bf16
// ---------------------------------------------------------------------------
__global__ __launch_bounds__(512) void tt_first(
        const float* __restrict__ z, const float* __restrict__ G0,
        __hip_bfloat16* __restrict__ res0) {
    __shared__ float sg[PP * RR];
    const int b = blockIdx.x;
    for (int x = threadIdx.x; x < PP * RR; x += 512) sg[x] = tanhf(G0[x]);
    __syncthreads();
    const float z0 = z[(size_t)b * DD + 0];
    const int r = threadIdx.x;
    float p = 1.0f, acc = 0.0f;
    #pragma unroll
    for (int j = 0; j < PP; ++j) { acc += sg[j * RR + r] * p; p *= z0; }
    res0[(size_t)b * RR + r] = __float2bfloat16(acc);
}

// ---------------------------------------------------------------------------
// Horner GEMM over j-panels.
//   acc = C_jtop; (acc *= zb^2; acc += C_{j-2}) x (NPAN-1); out = acc * zb^jbot
// A = res bf16 (unscaled) via global_load_lds, B = tanh(G)^T bf16 via
// global_load_lds. XOR-swizzled LDS layout (16B chunk c of row r stored at
// slot c ^ (r&7)) -> fragment ds_read_b128 are 2-way max (free).
// MID: grid (8, 64): x = n-block*2 + ksplit(s), jtop=8+s, jbot=s, out fp32
//      partial s at outp + s*BB*RR.
// LAST: grid (10, 64): x = j, BN=64, single panel, out fp32 partial at
//      outp + j*BB*OUTD, epilogue scales by zb^j.
// ---------------------------------------------------------------------------
template <int BN, int NPAN, bool LAST>
__global__ __launch_bounds__(256, 2) void tt_gemm_h(
        const __hip_bfloat16* __restrict__ resin,
        const __hip_bfloat16* __restrict__ tB,
        float* __restrict__ outp,
        const float* __restrict__ z, int d) {
    constexpr int BM = 128, BK = 64;
    constexpr int SN = BN / 32;       // n-subtiles per wave
    constexpr int BCPW = (BN / 8) / 4; // B chunks per wave

    __shared__ __hip_bfloat16 sA[BM * BK];
    __shared__ __hip_bfloat16 sB[BN * BK];

    const int tid  = threadIdx.x;
    const int lane = tid & 63;
    const int wave = tid >> 6;
    const int m0 = blockIdx.y * BM;

    int n0, jtop, jbot;
    if (LAST) {
        n0 = 0; jtop = jbot = blockIdx.x;
        outp += (size_t)blockIdx.x * ((size_t)BB * OUTD);
    } else {
        n0 = (blockIdx.x >> 1) * BN;
        const int s = blockIdx.x & 1;
        jtop = 8 + s; jbot = s;
        outp += (size_t)s * ((size_t)BB * RR);
    }

    const int wm = (wave >> 1) * 64;
    const int wn = (wave & 1) * (BN / 2);
    const int rq = (lane >> 4) * 4;

    // async staging lane roles
    const int asrow = lane >> 3;               // row within 8-row chunk
    const int acswz = ((lane & 7) ^ asrow) * 8; // swizzled 16B-chunk col (elems)

    f32x4 acc[4][SN];
    #pragma unroll
    for (int a = 0; a < 4; ++a)
        #pragma unroll
        for (int b = 0; b < SN; ++b) acc[a][b] = f32x4{0.f, 0.f, 0.f, 0.f};

    float zr2[16];
    if (NPAN > 1) {
        #pragma unroll
        for (int sm = 0; sm < 4; ++sm)
            #pragma unroll
            for (int r = 0; r < 4; ++r) {
                float zz = z[(size_t)(m0 + wm + sm * 16 + rq + r) * DD + d];
                zr2[sm * 4 + r] = zz * zz;
            }
    }

    #pragma unroll 1
    for (int pan = 0; pan < NPAN; ++pan) {
        const int j = jtop - 2 * pan;
        const size_t kb0 = (size_t)j * RR;

        #pragma unroll 1
        for (int kt = 0; kt < 8; ++kt) {
            const int kc = kt * 64;
            // A tile: 16 chunks of 8 rows x 128B, 4 per wave
            #pragma unroll
            for (int q = 0; q < 4; ++q) {
                const int ch = wave * 4 + q;
                gload_lds16(resin + (size_t)(m0 + ch * 8 + asrow) * RR + kc + acswz,
                            sA + ch * 512 + lane * 8);
            }
            // B tile
            #pragma unroll
            for (int q = 0; q < BCPW; ++q) {
                const int ch = wave * BCPW + q;
                gload_lds16(tB + (size_t)(n0 + ch * 8 + asrow) * KK + kb0 + kc + acswz,
                            sB + ch * 512 + lane * 8);
            }
            __syncthreads();

            #pragma unroll
            for (int ks = 0; ks < 2; ++ks) {
                const int q4 = ks * 4 + (lane >> 4);  // kb>>3
                bf16x8 av[4], bv[SN];
                #pragma unroll
                for (int s = 0; s < 4; ++s) {
                    const int row = wm + s * 16 + (lane & 15);
                    av[s] = *(const bf16x8*)(sA + row * 64 + ((q4 ^ (row & 7)) << 3));
                }
                #pragma unroll
                for (int s = 0; s < SN; ++s) {
                    const int row = wn + s * 16 + (lane & 15);
                    bv[s] = *(const bf16x8*)(sB + row * 64 + ((q4 ^ (row & 7)) << 3));
                }
                #pragma unroll
                for (int sm = 0; sm < 4; ++sm)
                    #pragma unroll
                    for (int sn = 0; sn < SN; ++sn)
                        acc[sm][sn] = __builtin_amdgcn_mfma_f32_16x16x32_bf16(
                            av[sm], bv[sn], acc[sm][sn], 0, 0, 0);
            }
            __syncthreads();
        }

        if (NPAN > 1 && pan != NPAN - 1) {
            #pragma unroll
            for (int sm = 0; sm < 4; ++sm)
                #pragma unroll
                for (int sn = 0; sn < SN; ++sn)
                    #pragma unroll
                    for (int r = 0; r < 4; ++r)
                        acc[sm][sn][r] *= zr2[sm * 4 + r];
        }
    }

    // epilogue: scale by zb^jbot per row, store f32 partial
    const int col = lane & 15;
    #pragma unroll
    for (int sm = 0; sm < 4; ++sm) {
        float zsc[4];
        #pragma unroll
        for (int r = 0; r < 4; ++r) {
            const int row = m0 + wm + sm * 16 + rq + r;
            const float zb = z[(size_t)row * DD + d];
            float p = 1.0f;
            for (int t = 0; t < jbot; ++t) p *= zb;
            zsc[r] = p;
        }
        #pragma unroll
        for (int sn = 0; sn < SN; ++sn)
            #pragma unroll
            for (int r = 0; r < 4; ++r) {
                const int grow = m0 + wm + sm * 16 + rq + r;
                const int gcol = n0 + wn + sn * 16 + col;
                outp[(size_t)grow * (LAST ? OUTD : RR) + gcol] = acc[sm][sn][r] * zsc[r];
            }
    }
}

// ---------------------------------------------------------------------------
// partial0 + partial1 (fp32) -> bf16 res for next stage.  n = BB*RR
// ---------------------------------------------------------------------------
__global__ __launch_bounds__(256) void sum2_bf16(
        const float* __restrict__ a, const float* __restrict__ b,
        __hip_bfloat16* __restrict__ o) {
    const size_t i = ((size_t)blockIdx.x * 256 + threadIdx.x) * 4;
    f32x4 x = *(const f32x4*)(a + i);
    f32x4 y = *(const f32x4*)(b + i);
    union { __hip_bfloat16 h[4]; uint2 u; } pk;
    #pragma unroll
    for (int k = 0; k < 4; ++k) pk.h[k] = __float2bfloat16(x[k] + y[k]);
    *(uint2*)(o + i) = pk.u;
}

// ---------------------------------------------------------------------------
// out[b,l] = sum_{s<10} parts[s][b][l]
// ---------------------------------------------------------------------------
__global__ __launch_bounds__(256) void reduce10(
        const float* __restrict__ p, float* __restrict__ o) {
    const size_t i = ((size_t)blockIdx.x * 256 + threadIdx.x) * 4;
    f32x4 s = f32x4{0.f, 0.f, 0.f, 0.f};
    #pragma unroll
    for (int q = 0; q < 10; ++q)
        s += *(const f32x4*)(p + (size_t)q * (BB * OUTD) + i);
    *(f32x4*)(o + i) = s;
}

// ---------------------------------------------------------------------------
extern "C" void kernel_launch(void* const* d_in, const int* in_sizes, int n_in,
                              void* d_out, int out_size, void* d_ws, size_t ws_size,
                              hipStream_t stream) {
    const float* z     = (const float*)d_in[0];
    const float* G0    = (const float*)d_in[1];
    const float* Gmid  = (const float*)d_in[2];
    const float* Glast = (const float*)d_in[3];
    float* out = (float*)d_out;

    char* ws = (char*)d_ws;
    __hip_bfloat16* resX = (__hip_bfloat16*)ws;                          // 8 MB
    __hip_bfloat16* resY = (__hip_bfloat16*)(ws + ((size_t)8 << 20));    // 8 MB
    float* P0            = (float*)(ws + ((size_t)16 << 20));            // 16 MB (P0,P1 contiguous)
    __hip_bfloat16* tBmid  = (__hip_bfloat16*)(ws + ((size_t)48 << 20)); // 31.5 MB
    __hip_bfloat16* tBlast = (__hip_bfloat16*)(ws + ((size_t)80 << 20)); // 0.64 MB
    float* LP = P0;  // last-core partials [10][BB*OUTD] alias P0/P1 region (20 MB)

    tanh_transpose_mid <<<dim3(16, 16, 60), dim3(32, 8), 0, stream>>>(Gmid,  tBmid);
    tanh_transpose_last<<<dim3(16, 2, 10),  dim3(32, 8), 0, stream>>>(Glast, tBlast);
    tt_first<<<BB, 512, 0, stream>>>(z, G0, resX);

    __hip_bfloat16* rin = resX;
    __hip_bfloat16* rnext = resY;
    for (int c = 0; c < 6; ++c) {
        tt_gemm_h<128, 5, false><<<dim3(8, BB / 128), 256, 0, stream>>>(
            rin, tBmid + (size_t)c * RR * KK, P0, z, c + 1);
        sum2_bf16<<<dim3((BB * RR) / 1024), 256, 0, stream>>>(
            P0, P0 + (size_t)BB * RR, rnext);
        __hip_bfloat16* t = rin; rin = rnext; rnext = t;
    }
    tt_gemm_h<64, 1, true><<<dim3(10, BB / 128), 256, 0, stream>>>(
        rin, tBlast, LP, z, 7);
    reduce10<<<dim3((BB * OUTD) / 1024), 256, 0, stream>>>(LP, out);
}